// Round 3
// baseline (800.504 us; speedup 1.0000x reference)
//
#include <hip/hip_runtime.h>
#include <hip/hip_bf16.h>

#define NN 16384      // nodes
#define EE 8192       // edges
#define DD 128        // feature dim (in == out)
#define CSR_STRIDE 128   // max node degree slot (actual max ~70, Binomial(8192,.005))
#define CSC_STRIDE 192   // max edge degree slot (actual max ~125, Binomial(16384,.005))
#define GEMM_BLOCKS 512  // NN/32 tiles of the x@W^T GEMM, fused into k1's grid

typedef float f4 __attribute__((ext_vector_type(4)));

// ---------------- workspace layout (bytes) ----------------
// dvih      : NN f32                      @ 0          (64 KB)
// csr_cnt   : NN i32                      @ 65536      (64 KB)
// edge_cnt  : EE i32                      @ 131072     (32 KB)
// csr_idx   : NN*CSR_STRIDE i32           @ 163840     (8 MB)
// csc_idx   : EE*CSC_STRIDE i32           @ 8552448    (6 MB)
// xw        : NN*DD f32                   @ 14843904   (8 MB)
// y2        : EE*DD f32                   @ 23232512   (4 MB)
// total ~27.4 MB

// K1 (fused): heterogeneous grid.
//   blocks [0, GEMM_BLOCKS)          : xw = x @ W^T tile (overlaps with HBM-bound parse)
//   blocks [GEMM_BLOCKS, +NN)        : parse one H row -> dvih, CSR, CSC (atomic cursors)
// H is read with nontemporal loads: it is one-shot 512 MiB traffic and must not
// evict xw / csc_idx from L2 ahead of K2.
__global__ __launch_bounds__(256) void k1_fused(
    const float* __restrict__ H,
    const float* __restrict__ x,
    const float* __restrict__ W,
    float* __restrict__ xw,
    float* __restrict__ dvih,
    int* __restrict__ csr_cnt,
    int* __restrict__ csr_idx,
    int* __restrict__ edge_cnt,
    int* __restrict__ csc_idx)
{
    // shared pool: GEMM path needs 32*132 + 64*132 floats (~50.7 KB); parse path
    // aliases a tiny prefix. 160 KB LDS / 50.7 KB -> 3 blocks/CU, 12 waves/CU:
    // ample in-flight loads (12*8*1KB = 98 KB/CU) to saturate HBM.
    __shared__ float smem[32 * 132 + 64 * 132];
    const int t = threadIdx.x;

    if (blockIdx.x < GEMM_BLOCKS) {
        // ---------------- GEMM tile: 32 rows of x @ W^T ----------------
        float* sA = smem;               // 32 x 132
        float* sW = smem + 32 * 132;    // 64 x 132
        const int m0 = blockIdx.x * 32;

#pragma unroll
        for (int r = 0; r < 16; ++r) {
            int i = t + 256 * r;            // 0..4095
            int row = i >> 7, col = i & 127;
            sA[row * 132 + col] = x[(size_t)(m0 + row) * DD + col];
        }

        const int jg = t & 15;    // j-group -> 4 consecutive j
        const int mg = t >> 4;    // 0..15   -> 2 consecutive m
        const int m2 = mg * 2;
        const int j4 = jg * 4;

        for (int h = 0; h < 2; ++h) {
            __syncthreads();
#pragma unroll
            for (int r = 0; r < 32; ++r) {
                int i = t + 256 * r;        // 0..8191
                int row = i >> 7, col = i & 127;
                sW[row * 132 + col] = W[(size_t)(h * 64 + row) * DD + col];
            }
            __syncthreads();

            float acc0[4] = {0.f, 0.f, 0.f, 0.f};
            float acc1[4] = {0.f, 0.f, 0.f, 0.f};
#pragma unroll 4
            for (int k = 0; k < 128; k += 4) {
                float4 a0 = *(const float4*)&sA[m2 * 132 + k];
                float4 a1 = *(const float4*)&sA[(m2 + 1) * 132 + k];
#pragma unroll
                for (int jj = 0; jj < 4; ++jj) {
                    float4 w = *(const float4*)&sW[(j4 + jj) * 132 + k];
                    acc0[jj] += a0.x*w.x + a0.y*w.y + a0.z*w.z + a0.w*w.w;
                    acc1[jj] += a1.x*w.x + a1.y*w.y + a1.z*w.z + a1.w*w.w;
                }
            }
#pragma unroll
            for (int jj = 0; jj < 4; ++jj) {
                xw[(size_t)(m0 + m2)     * DD + h * 64 + j4 + jj] = acc0[jj];
                xw[(size_t)(m0 + m2 + 1) * DD + h * 64 + j4 + jj] = acc1[jj];
            }
        }
    } else {
        // ---------------- parse one H row ----------------
        const int n = blockIdx.x - GEMM_BLOCKS;
        int* s_cnt  = (int*)smem;
        int* s_list = (int*)smem + 4;      // [CSR_STRIDE]
        if (t == 0) *s_cnt = 0;
        __syncthreads();

        const f4* row = (const f4*)(H + (size_t)n * EE);
#pragma unroll
        for (int j = 0; j < 8; ++j) {
            int idx = t + 256 * j;          // float4 index in row (0..2047)
            f4 v = __builtin_nontemporal_load(row + idx);
            int base = idx * 4;
            if (v.x != 0.0f) { int p = atomicAdd(s_cnt, 1); if (p < CSR_STRIDE) s_list[p] = base + 0; }
            if (v.y != 0.0f) { int p = atomicAdd(s_cnt, 1); if (p < CSR_STRIDE) s_list[p] = base + 1; }
            if (v.z != 0.0f) { int p = atomicAdd(s_cnt, 1); if (p < CSR_STRIDE) s_list[p] = base + 2; }
            if (v.w != 0.0f) { int p = atomicAdd(s_cnt, 1); if (p < CSR_STRIDE) s_list[p] = base + 3; }
        }
        __syncthreads();

        int cnt = *s_cnt; if (cnt > CSR_STRIDE) cnt = CSR_STRIDE;
        if (t < cnt) {
            int e = s_list[t];
            csr_idx[(size_t)n * CSR_STRIDE + t] = e;
            int pos = atomicAdd(&edge_cnt[e], 1);       // device-scope, builds CSC
            if (pos < CSC_STRIDE) csc_idx[(size_t)e * CSC_STRIDE + pos] = n;
        }
        if (t == 0) {
            csr_cnt[n] = cnt;
            dvih[n] = (cnt > 0) ? (1.0f / sqrtf((float)cnt)) : 0.0f;
        }
    }
}

// K2: per edge e: y2[e,d] = dei[e] * sum_{n in col(e)} dvih[n] * xw[n,d]
// 2 edges per 256-thread block.
__global__ __launch_bounds__(256) void k2_edge_gather(
    const float* __restrict__ xw,
    const float* __restrict__ dvih,
    const int* __restrict__ edge_cnt,
    const int* __restrict__ csc_idx,
    float* __restrict__ y2)
{
    const int sub = threadIdx.x >> 7;       // which edge within block
    const int t   = threadIdx.x & 127;      // feature dim
    const int e   = blockIdx.x * 2 + sub;
    __shared__ int   s_lst[2][CSC_STRIDE];
    __shared__ float s_dv[2][CSC_STRIDE];

    int cnt = edge_cnt[e];
    int ccnt = cnt > CSC_STRIDE ? CSC_STRIDE : cnt;
    for (int i = t; i < ccnt; i += 128) {
        int n = csc_idx[(size_t)e * CSC_STRIDE + i];
        s_lst[sub][i] = n;
        s_dv[sub][i]  = dvih[n];
    }
    __syncthreads();

    float s = 0.0f;
    int i = 0;
    for (; i + 8 <= ccnt; i += 8) {
        float partial = 0.0f;
#pragma unroll
        for (int u = 0; u < 8; ++u) {
            partial += s_dv[sub][i + u] * xw[(size_t)s_lst[sub][i + u] * DD + t];
        }
        s += partial;
    }
    for (; i < ccnt; ++i) s += s_dv[sub][i] * xw[(size_t)s_lst[sub][i] * DD + t];

    float dei = (cnt > 0) ? (1.0f / (float)cnt) : 0.0f;
    y2[(size_t)e * DD + t] = s * dei;
}

// K3: per node n: out[n,d] = dvih[n] * sum_{e in row(n)} y2[e,d] + b[d]
// 2 nodes per 256-thread block.
__global__ __launch_bounds__(256) void k3_node_gather(
    const float* __restrict__ y2,
    const float* __restrict__ dvih,
    const int* __restrict__ csr_cnt,
    const int* __restrict__ csr_idx,
    const float* __restrict__ b,
    float* __restrict__ out)
{
    const int sub = threadIdx.x >> 7;
    const int t   = threadIdx.x & 127;      // feature dim
    const int n   = blockIdx.x * 2 + sub;
    __shared__ int s_lst[2][CSR_STRIDE];

    int cnt = csr_cnt[n];
    if (t < cnt) s_lst[sub][t] = csr_idx[(size_t)n * CSR_STRIDE + t];
    __syncthreads();

    float s = 0.0f;
    int i = 0;
    for (; i + 8 <= cnt; i += 8) {
        float partial = 0.0f;
#pragma unroll
        for (int u = 0; u < 8; ++u) {
            partial += y2[(size_t)s_lst[sub][i + u] * DD + t];
        }
        s += partial;
    }
    for (; i < cnt; ++i) s += y2[(size_t)s_lst[sub][i] * DD + t];

    out[(size_t)n * DD + t] = dvih[n] * s + b[t];
}

extern "C" void kernel_launch(void* const* d_in, const int* in_sizes, int n_in,
                              void* d_out, int out_size, void* d_ws, size_t ws_size,
                              hipStream_t stream) {
    const float* x = (const float*)d_in[0];   // [16384,128]
    const float* H = (const float*)d_in[1];   // [16384,8192]
    const float* W = (const float*)d_in[2];   // [128,128]
    const float* b = (const float*)d_in[3];   // [128]
    float* out = (float*)d_out;

    char* ws = (char*)d_ws;
    float* dvih    = (float*)(ws + 0);
    int*   csr_cnt = (int*)  (ws + 65536);
    int*   edge_cnt= (int*)  (ws + 131072);
    int*   csr_idx = (int*)  (ws + 163840);
    int*   csc_idx = (int*)  (ws + 8552448);
    float* xw      = (float*)(ws + 14843904);
    float* y2      = (float*)(ws + 23232512);

    // zero the edge cursors (must complete before any k1 atomicAdd)
    hipMemsetAsync(edge_cnt, 0, EE * sizeof(int), stream);

    k1_fused<<<GEMM_BLOCKS + NN, 256, 0, stream>>>(H, x, W, xw, dvih,
                                                   csr_cnt, csr_idx, edge_cnt, csc_idx);
    k2_edge_gather<<<EE / 2, 256, 0, stream>>>(xw, dvih, edge_cnt, csc_idx, y2);
    k3_node_gather<<<NN / 2, 256, 0, stream>>>(y2, dvih, csr_cnt, csr_idx, b, out);
}

// Round 4
// 765.119 us; speedup vs baseline: 1.0462x; 1.0462x over previous
//
#include <hip/hip_runtime.h>
#include <hip/hip_bf16.h>

#define NN 16384      // nodes
#define EE 8192       // edges
#define DD 128        // feature dim (in == out)
#define CSR_STRIDE 128   // max node degree slot (actual max ~70, Binomial(8192,.005))
#define CSC_STRIDE 192   // max edge degree slot (actual max ~125, Binomial(16384,.005))

// ---------------- workspace layout (bytes) ----------------
// dvih      : NN f32                      @ 0          (64 KB)
// csr_cnt   : NN i32                      @ 65536      (64 KB)
// edge_cnt  : EE i32                      @ 131072     (32 KB)
// csr_idx   : NN*CSR_STRIDE i32           @ 163840     (8 MB)
// csc_idx   : EE*CSC_STRIDE i32           @ 8552448    (6 MB)
// xw        : NN*DD f32                   @ 14843904   (8 MB)
// y2        : EE*DD f32                   @ 23232512   (4 MB)
// total ~27.4 MB

// G: xw = x @ W^T  (M=16384, N=128, K=128, fp32 LDS-tiled). Also zeroes the
// edge cursors (runs before k1_parse in stream order).
__global__ __launch_bounds__(256) void g_gemm(
    const float* __restrict__ x,
    const float* __restrict__ W,
    float* __restrict__ xw,
    int* __restrict__ edge_cnt)
{
    const int t = threadIdx.x;
    {
        int tid = blockIdx.x * 256 + t;
        if (tid < EE) edge_cnt[tid] = 0;
    }

    __shared__ float sA[32 * 132];
    __shared__ float sW[64 * 132];
    const int m0 = blockIdx.x * 32;

#pragma unroll
    for (int r = 0; r < 16; ++r) {
        int i = t + 256 * r;            // 0..4095
        int row = i >> 7, col = i & 127;
        sA[row * 132 + col] = x[(size_t)(m0 + row) * DD + col];
    }

    const int jg = t & 15;    // j-group -> 4 consecutive j
    const int mg = t >> 4;    // 0..15   -> 2 consecutive m
    const int m2 = mg * 2;
    const int j4 = jg * 4;

    for (int h = 0; h < 2; ++h) {
        __syncthreads();
#pragma unroll
        for (int r = 0; r < 32; ++r) {
            int i = t + 256 * r;        // 0..8191
            int row = i >> 7, col = i & 127;
            sW[row * 132 + col] = W[(size_t)(h * 64 + row) * DD + col];
        }
        __syncthreads();

        float acc0[4] = {0.f, 0.f, 0.f, 0.f};
        float acc1[4] = {0.f, 0.f, 0.f, 0.f};
#pragma unroll 4
        for (int k = 0; k < 128; k += 4) {
            float4 a0 = *(const float4*)&sA[m2 * 132 + k];
            float4 a1 = *(const float4*)&sA[(m2 + 1) * 132 + k];
#pragma unroll
            for (int jj = 0; jj < 4; ++jj) {
                float4 w = *(const float4*)&sW[(j4 + jj) * 132 + k];
                acc0[jj] += a0.x*w.x + a0.y*w.y + a0.z*w.z + a0.w*w.w;
                acc1[jj] += a1.x*w.x + a1.y*w.y + a1.z*w.z + a1.w*w.w;
            }
        }
#pragma unroll
        for (int jj = 0; jj < 4; ++jj) {
            xw[(size_t)(m0 + m2)     * DD + h * 64 + j4 + jj] = acc0[jj];
            xw[(size_t)(m0 + m2 + 1) * DD + h * 64 + j4 + jj] = acc1[jj];
        }
    }
}

// K1: one full pass over H. Per block = one node row (32 KB contiguous).
// Small LDS footprint -> 8 blocks/CU, 32 waves: saturates HBM (R3 showed that
// inflating this kernel's LDS to 50 KB costs ~33 us).
__global__ __launch_bounds__(256) void k1_parse(
    const float* __restrict__ H,
    float* __restrict__ dvih,
    int* __restrict__ csr_cnt,
    int* __restrict__ csr_idx,
    int* __restrict__ edge_cnt,
    int* __restrict__ csc_idx)
{
    const int n = blockIdx.x;
    const int t = threadIdx.x;
    __shared__ int s_cnt;
    __shared__ int s_list[CSR_STRIDE];
    if (t == 0) s_cnt = 0;
    __syncthreads();

    const float4* row = (const float4*)(H + (size_t)n * EE);
#pragma unroll
    for (int j = 0; j < 8; ++j) {
        int idx = t + 256 * j;          // float4 index in row (0..2047)
        float4 v = row[idx];
        int base = idx * 4;
        if (v.x != 0.0f) { int p = atomicAdd(&s_cnt, 1); if (p < CSR_STRIDE) s_list[p] = base + 0; }
        if (v.y != 0.0f) { int p = atomicAdd(&s_cnt, 1); if (p < CSR_STRIDE) s_list[p] = base + 1; }
        if (v.z != 0.0f) { int p = atomicAdd(&s_cnt, 1); if (p < CSR_STRIDE) s_list[p] = base + 2; }
        if (v.w != 0.0f) { int p = atomicAdd(&s_cnt, 1); if (p < CSR_STRIDE) s_list[p] = base + 3; }
    }
    __syncthreads();

    int cnt = s_cnt; if (cnt > CSR_STRIDE) cnt = CSR_STRIDE;
    if (t < cnt) {
        int e = s_list[t];
        csr_idx[(size_t)n * CSR_STRIDE + t] = e;
        int pos = atomicAdd(&edge_cnt[e], 1);       // device-scope, builds CSC
        if (pos < CSC_STRIDE) csc_idx[(size_t)e * CSC_STRIDE + pos] = n;
    }
    if (t == 0) {
        csr_cnt[n] = cnt;
        dvih[n] = (cnt > 0) ? (1.0f / sqrtf((float)cnt)) : 0.0f;
    }
}

// K2: per edge e: y2[e,:] = dei[e] * sum_{n in col(e)} dvih[n] * xw[n,:]
// 2 edges per 256-thread block; per edge, 4 groups x 32 lanes of float4
// gathers (4 independent 16B loads in flight), LDS cross-group reduce.
__global__ __launch_bounds__(256) void k2_edge_gather(
    const float* __restrict__ xw,
    const float* __restrict__ dvih,
    const int* __restrict__ edge_cnt,
    const int* __restrict__ csc_idx,
    float* __restrict__ y2)
{
    const int t    = threadIdx.x;
    const int sub  = t >> 7;        // edge within block
    const int tt   = t & 127;
    const int grp  = tt >> 5;       // 0..3
    const int lane = tt & 31;       // float4 column
    const int e    = blockIdx.x * 2 + sub;

    __shared__ int    s_lst[2][CSC_STRIDE];
    __shared__ float  s_dv[2][CSC_STRIDE];
    __shared__ float4 s_red[2][3][32];

    int cnt = edge_cnt[e];
    int ccnt = cnt > CSC_STRIDE ? CSC_STRIDE : cnt;
    for (int i = tt; i < ccnt; i += 128) {
        int n = csc_idx[(size_t)e * CSC_STRIDE + i];
        s_lst[sub][i] = n;
        s_dv[sub][i]  = dvih[n];
    }
    __syncthreads();

    const float4* xw4 = (const float4*)xw;
    float ax = 0.f, ay = 0.f, az = 0.f, aw = 0.f;
    int i = grp;
    for (; i + 16 <= ccnt; i += 16) {
        float4 v0 = xw4[(size_t)s_lst[sub][i     ] * 32 + lane];
        float4 v1 = xw4[(size_t)s_lst[sub][i +  4] * 32 + lane];
        float4 v2 = xw4[(size_t)s_lst[sub][i +  8] * 32 + lane];
        float4 v3 = xw4[(size_t)s_lst[sub][i + 12] * 32 + lane];
        float f0 = s_dv[sub][i], f1 = s_dv[sub][i + 4];
        float f2 = s_dv[sub][i + 8], f3 = s_dv[sub][i + 12];
        ax += f0*v0.x + f1*v1.x + f2*v2.x + f3*v3.x;
        ay += f0*v0.y + f1*v1.y + f2*v2.y + f3*v3.y;
        az += f0*v0.z + f1*v1.z + f2*v2.z + f3*v3.z;
        aw += f0*v0.w + f1*v1.w + f2*v2.w + f3*v3.w;
    }
    for (; i < ccnt; i += 4) {
        float4 v = xw4[(size_t)s_lst[sub][i] * 32 + lane];
        float f = s_dv[sub][i];
        ax += f*v.x; ay += f*v.y; az += f*v.z; aw += f*v.w;
    }

    if (grp) { s_red[sub][grp - 1][lane] = make_float4(ax, ay, az, aw); }
    __syncthreads();
    if (grp == 0) {
        float4 r0 = s_red[sub][0][lane];
        float4 r1 = s_red[sub][1][lane];
        float4 r2 = s_red[sub][2][lane];
        float dei = (cnt > 0) ? (1.0f / (float)cnt) : 0.0f;
        float4 o = make_float4((ax + r0.x + r1.x + r2.x) * dei,
                               (ay + r0.y + r1.y + r2.y) * dei,
                               (az + r0.z + r1.z + r2.z) * dei,
                               (aw + r0.w + r1.w + r2.w) * dei);
        ((float4*)y2)[(size_t)e * 32 + lane] = o;
    }
}

// K3: per node n: out[n,:] = dvih[n] * sum_{e in row(n)} y2[e,:] + b[:]
// Same float4 gather structure as K2.
__global__ __launch_bounds__(256) void k3_node_gather(
    const float* __restrict__ y2,
    const float* __restrict__ dvih,
    const int* __restrict__ csr_cnt,
    const int* __restrict__ csr_idx,
    const float* __restrict__ b,
    float* __restrict__ out)
{
    const int t    = threadIdx.x;
    const int sub  = t >> 7;
    const int tt   = t & 127;
    const int grp  = tt >> 5;
    const int lane = tt & 31;
    const int n    = blockIdx.x * 2 + sub;

    __shared__ int    s_lst[2][CSR_STRIDE];
    __shared__ float4 s_red[2][3][32];

    int cnt = csr_cnt[n];
    if (tt < cnt) s_lst[sub][tt] = csr_idx[(size_t)n * CSR_STRIDE + tt];
    __syncthreads();

    const float4* y24 = (const float4*)y2;
    float ax = 0.f, ay = 0.f, az = 0.f, aw = 0.f;
    int i = grp;
    for (; i + 16 <= cnt; i += 16) {
        float4 v0 = y24[(size_t)s_lst[sub][i     ] * 32 + lane];
        float4 v1 = y24[(size_t)s_lst[sub][i +  4] * 32 + lane];
        float4 v2 = y24[(size_t)s_lst[sub][i +  8] * 32 + lane];
        float4 v3 = y24[(size_t)s_lst[sub][i + 12] * 32 + lane];
        ax += v0.x + v1.x + v2.x + v3.x;
        ay += v0.y + v1.y + v2.y + v3.y;
        az += v0.z + v1.z + v2.z + v3.z;
        aw += v0.w + v1.w + v2.w + v3.w;
    }
    for (; i < cnt; i += 4) {
        float4 v = y24[(size_t)s_lst[sub][i] * 32 + lane];
        ax += v.x; ay += v.y; az += v.z; aw += v.w;
    }

    if (grp) { s_red[sub][grp - 1][lane] = make_float4(ax, ay, az, aw); }
    __syncthreads();
    if (grp == 0) {
        float4 r0 = s_red[sub][0][lane];
        float4 r1 = s_red[sub][1][lane];
        float4 r2 = s_red[sub][2][lane];
        float dv = dvih[n];
        float4 bb = ((const float4*)b)[lane];
        float4 o = make_float4((ax + r0.x + r1.x + r2.x) * dv + bb.x,
                               (ay + r0.y + r1.y + r2.y) * dv + bb.y,
                               (az + r0.z + r1.z + r2.z) * dv + bb.z,
                               (aw + r0.w + r1.w + r2.w) * dv + bb.w);
        ((float4*)out)[(size_t)n * 32 + lane] = o;
    }
}

extern "C" void kernel_launch(void* const* d_in, const int* in_sizes, int n_in,
                              void* d_out, int out_size, void* d_ws, size_t ws_size,
                              hipStream_t stream) {
    const float* x = (const float*)d_in[0];   // [16384,128]
    const float* H = (const float*)d_in[1];   // [16384,8192]
    const float* W = (const float*)d_in[2];   // [128,128]
    const float* b = (const float*)d_in[3];   // [128]
    float* out = (float*)d_out;

    char* ws = (char*)d_ws;
    float* dvih    = (float*)(ws + 0);
    int*   csr_cnt = (int*)  (ws + 65536);
    int*   edge_cnt= (int*)  (ws + 131072);
    int*   csr_idx = (int*)  (ws + 163840);
    int*   csc_idx = (int*)  (ws + 8552448);
    float* xw      = (float*)(ws + 14843904);
    float* y2      = (float*)(ws + 23232512);

    g_gemm<<<NN / 32, 256, 0, stream>>>(x, W, xw, edge_cnt);
    k1_parse<<<NN, 256, 0, stream>>>(H, dvih, csr_cnt, csr_idx, edge_cnt, csc_idx);
    k2_edge_gather<<<EE / 2, 256, 0, stream>>>(xw, dvih, edge_cnt, csc_idx, y2);
    k3_node_gather<<<NN / 2, 256, 0, stream>>>(y2, dvih, csr_cnt, csr_idx, b, out);
}

// Round 5
// 754.719 us; speedup vs baseline: 1.0607x; 1.0138x over previous
//
#include <hip/hip_runtime.h>
#include <hip/hip_bf16.h>

#define NN 16384      // nodes
#define EE 8192       // edges
#define DD 128        // feature dim (in == out)
#define CSR_STRIDE 128   // max node degree slot (mean 41, sd 6.4 -> 13 sigma margin)
#define CSC_STRIDE 192   // max edge degree slot (mean 82, sd 9 -> 12 sigma margin)

// bf16 pack/unpack (RNE). Intermediates xw/y2 stored bf16 to halve gather
// traffic and make them per-XCD-L2 resident (4 MB / 2 MB); accum stays fp32.
__device__ __forceinline__ unsigned short f2bf(float f) {
    union { float f; unsigned u; } c; c.f = f;
    unsigned u = c.u + (0x7FFFu + ((c.u >> 16) & 1u));
    return (unsigned short)(u >> 16);
}
__device__ __forceinline__ float bf2f(unsigned short h) {
    union { unsigned u; float f; } c; c.u = ((unsigned)h) << 16;
    return c.f;
}

// ---------------- workspace layout (bytes) ----------------
// dvih      : NN f32                      @ 0          (64 KB)
// csr_cnt   : NN i32                      @ 65536      (64 KB)
// edge_cnt  : EE i32                      @ 131072     (32 KB)
// csr_idx   : NN*CSR_STRIDE i32           @ 163840     (8 MB)
// csc_idx   : EE*CSC_STRIDE i32           @ 8552448    (6 MB)
// xw        : NN*DD bf16                  @ 14843904   (4 MB)
// y2        : EE*DD bf16                  @ 19038208   (2 MB)
// total ~21 MB

// G: xw = bf16(x @ W^T)  (M=16384, N=128, K=128, fp32 LDS-tiled). Also zeroes
// the edge cursors (runs before k1_parse in stream order).
__global__ __launch_bounds__(256) void g_gemm(
    const float* __restrict__ x,
    const float* __restrict__ W,
    ushort4* __restrict__ xwb,          // [NN][32] ushort4 rows
    int* __restrict__ edge_cnt)
{
    const int t = threadIdx.x;
    {
        int tid = blockIdx.x * 256 + t;
        if (tid < EE) edge_cnt[tid] = 0;
    }

    __shared__ float sA[32 * 132];
    __shared__ float sW[64 * 132];
    const int m0 = blockIdx.x * 32;

#pragma unroll
    for (int r = 0; r < 16; ++r) {
        int i = t + 256 * r;            // 0..4095
        int row = i >> 7, col = i & 127;
        sA[row * 132 + col] = x[(size_t)(m0 + row) * DD + col];
    }

    const int jg = t & 15;    // j-group -> 4 consecutive j
    const int mg = t >> 4;    // 0..15   -> 2 consecutive m
    const int m2 = mg * 2;
    const int j4 = jg * 4;

    for (int h = 0; h < 2; ++h) {
        __syncthreads();
#pragma unroll
        for (int r = 0; r < 32; ++r) {
            int i = t + 256 * r;        // 0..8191
            int row = i >> 7, col = i & 127;
            sW[row * 132 + col] = W[(size_t)(h * 64 + row) * DD + col];
        }
        __syncthreads();

        float acc0[4] = {0.f, 0.f, 0.f, 0.f};
        float acc1[4] = {0.f, 0.f, 0.f, 0.f};
#pragma unroll 4
        for (int k = 0; k < 128; k += 4) {
            float4 a0 = *(const float4*)&sA[m2 * 132 + k];
            float4 a1 = *(const float4*)&sA[(m2 + 1) * 132 + k];
#pragma unroll
            for (int jj = 0; jj < 4; ++jj) {
                float4 w = *(const float4*)&sW[(j4 + jj) * 132 + k];
                acc0[jj] += a0.x*w.x + a0.y*w.y + a0.z*w.z + a0.w*w.w;
                acc1[jj] += a1.x*w.x + a1.y*w.y + a1.z*w.z + a1.w*w.w;
            }
        }
        ushort4 p0, p1;
        p0.x = f2bf(acc0[0]); p0.y = f2bf(acc0[1]); p0.z = f2bf(acc0[2]); p0.w = f2bf(acc0[3]);
        p1.x = f2bf(acc1[0]); p1.y = f2bf(acc1[1]); p1.z = f2bf(acc1[2]); p1.w = f2bf(acc1[3]);
        xwb[(size_t)(m0 + m2)     * 32 + h * 16 + jg] = p0;
        xwb[(size_t)(m0 + m2 + 1) * 32 + h * 16 + jg] = p1;
    }
}

// K1: one full pass over H. Per block = one node row (32 KB contiguous).
// Small LDS footprint -> 8 blocks/CU, 32 waves: saturates HBM (R3 showed that
// inflating this kernel's LDS to 50 KB costs ~33 us).
__global__ __launch_bounds__(256) void k1_parse(
    const float* __restrict__ H,
    float* __restrict__ dvih,
    int* __restrict__ csr_cnt,
    int* __restrict__ csr_idx,
    int* __restrict__ edge_cnt,
    int* __restrict__ csc_idx)
{
    const int n = blockIdx.x;
    const int t = threadIdx.x;
    __shared__ int s_cnt;
    __shared__ int s_list[CSR_STRIDE];
    if (t == 0) s_cnt = 0;
    __syncthreads();

    const float4* row = (const float4*)(H + (size_t)n * EE);
#pragma unroll
    for (int j = 0; j < 8; ++j) {
        int idx = t + 256 * j;          // float4 index in row (0..2047)
        float4 v = row[idx];
        int base = idx * 4;
        if (v.x != 0.0f) { int p = atomicAdd(&s_cnt, 1); if (p < CSR_STRIDE) s_list[p] = base + 0; }
        if (v.y != 0.0f) { int p = atomicAdd(&s_cnt, 1); if (p < CSR_STRIDE) s_list[p] = base + 1; }
        if (v.z != 0.0f) { int p = atomicAdd(&s_cnt, 1); if (p < CSR_STRIDE) s_list[p] = base + 2; }
        if (v.w != 0.0f) { int p = atomicAdd(&s_cnt, 1); if (p < CSR_STRIDE) s_list[p] = base + 3; }
    }
    __syncthreads();

    int cnt = s_cnt; if (cnt > CSR_STRIDE) cnt = CSR_STRIDE;
    if (t < cnt) {
        int e = s_list[t];
        csr_idx[(size_t)n * CSR_STRIDE + t] = e;
        int pos = atomicAdd(&edge_cnt[e], 1);       // device-scope, builds CSC
        if (pos < CSC_STRIDE) csc_idx[(size_t)e * CSC_STRIDE + pos] = n;
    }
    if (t == 0) {
        csr_cnt[n] = cnt;
        dvih[n] = (cnt > 0) ? (1.0f / sqrtf((float)cnt)) : 0.0f;
    }
}

// K2: per edge e: y2[e,:] = bf16( dei[e] * sum_{n in col(e)} dvih[n]*xw[n,:] )
// 2 edges per 256-thread block; per edge, 4 groups x 32 lanes; each lane owns
// 4 consecutive features loaded as one ushort4 (8B) -> 256B/row coalesced.
__global__ __launch_bounds__(256) void k2_edge_gather(
    const ushort4* __restrict__ xwb,
    const float* __restrict__ dvih,
    const int* __restrict__ edge_cnt,
    const int* __restrict__ csc_idx,
    ushort4* __restrict__ y2b)
{
    const int t    = threadIdx.x;
    const int sub  = t >> 7;        // edge within block
    const int tt   = t & 127;
    const int grp  = tt >> 5;       // 0..3
    const int lane = tt & 31;       // ushort4 column (4 features)
    const int e    = blockIdx.x * 2 + sub;

    __shared__ int    s_lst[2][CSC_STRIDE];
    __shared__ float  s_dv[2][CSC_STRIDE];
    __shared__ float4 s_red[2][3][32];

    int cnt = edge_cnt[e];
    int ccnt = cnt > CSC_STRIDE ? CSC_STRIDE : cnt;
    for (int i = tt; i < ccnt; i += 128) {
        int n = csc_idx[(size_t)e * CSC_STRIDE + i];
        s_lst[sub][i] = n;
        s_dv[sub][i]  = dvih[n];
    }
    __syncthreads();

    float ax = 0.f, ay = 0.f, az = 0.f, aw = 0.f;
    int i = grp;
    for (; i + 16 <= ccnt; i += 16) {
        ushort4 v0 = xwb[(size_t)s_lst[sub][i     ] * 32 + lane];
        ushort4 v1 = xwb[(size_t)s_lst[sub][i +  4] * 32 + lane];
        ushort4 v2 = xwb[(size_t)s_lst[sub][i +  8] * 32 + lane];
        ushort4 v3 = xwb[(size_t)s_lst[sub][i + 12] * 32 + lane];
        float f0 = s_dv[sub][i], f1 = s_dv[sub][i + 4];
        float f2 = s_dv[sub][i + 8], f3 = s_dv[sub][i + 12];
        ax += f0*bf2f(v0.x) + f1*bf2f(v1.x) + f2*bf2f(v2.x) + f3*bf2f(v3.x);
        ay += f0*bf2f(v0.y) + f1*bf2f(v1.y) + f2*bf2f(v2.y) + f3*bf2f(v3.y);
        az += f0*bf2f(v0.z) + f1*bf2f(v1.z) + f2*bf2f(v2.z) + f3*bf2f(v3.z);
        aw += f0*bf2f(v0.w) + f1*bf2f(v1.w) + f2*bf2f(v2.w) + f3*bf2f(v3.w);
    }
    for (; i < ccnt; i += 4) {
        ushort4 v = xwb[(size_t)s_lst[sub][i] * 32 + lane];
        float f = s_dv[sub][i];
        ax += f*bf2f(v.x); ay += f*bf2f(v.y); az += f*bf2f(v.z); aw += f*bf2f(v.w);
    }

    if (grp) { s_red[sub][grp - 1][lane] = make_float4(ax, ay, az, aw); }
    __syncthreads();
    if (grp == 0) {
        float4 r0 = s_red[sub][0][lane];
        float4 r1 = s_red[sub][1][lane];
        float4 r2 = s_red[sub][2][lane];
        float dei = (cnt > 0) ? (1.0f / (float)cnt) : 0.0f;
        ushort4 o;
        o.x = f2bf((ax + r0.x + r1.x + r2.x) * dei);
        o.y = f2bf((ay + r0.y + r1.y + r2.y) * dei);
        o.z = f2bf((az + r0.z + r1.z + r2.z) * dei);
        o.w = f2bf((aw + r0.w + r1.w + r2.w) * dei);
        y2b[(size_t)e * 32 + lane] = o;
    }
}

// K3: per node n: out[n,:] = dvih[n] * sum_{e in row(n)} y2[e,:] + b[:]
// Same structure as K2; fp32 output.
__global__ __launch_bounds__(256) void k3_node_gather(
    const ushort4* __restrict__ y2b,
    const float* __restrict__ dvih,
    const int* __restrict__ csr_cnt,
    const int* __restrict__ csr_idx,
    const float* __restrict__ b,
    float* __restrict__ out)
{
    const int t    = threadIdx.x;
    const int sub  = t >> 7;
    const int tt   = t & 127;
    const int grp  = tt >> 5;
    const int lane = tt & 31;       // 4 consecutive features
    const int n    = blockIdx.x * 2 + sub;

    __shared__ int    s_lst[2][CSR_STRIDE];
    __shared__ float4 s_red[2][3][32];

    int cnt = csr_cnt[n];
    if (tt < cnt) s_lst[sub][tt] = csr_idx[(size_t)n * CSR_STRIDE + tt];
    __syncthreads();

    float ax = 0.f, ay = 0.f, az = 0.f, aw = 0.f;
    int i = grp;
    for (; i + 16 <= cnt; i += 16) {
        ushort4 v0 = y2b[(size_t)s_lst[sub][i     ] * 32 + lane];
        ushort4 v1 = y2b[(size_t)s_lst[sub][i +  4] * 32 + lane];
        ushort4 v2 = y2b[(size_t)s_lst[sub][i +  8] * 32 + lane];
        ushort4 v3 = y2b[(size_t)s_lst[sub][i + 12] * 32 + lane];
        ax += bf2f(v0.x) + bf2f(v1.x) + bf2f(v2.x) + bf2f(v3.x);
        ay += bf2f(v0.y) + bf2f(v1.y) + bf2f(v2.y) + bf2f(v3.y);
        az += bf2f(v0.z) + bf2f(v1.z) + bf2f(v2.z) + bf2f(v3.z);
        aw += bf2f(v0.w) + bf2f(v1.w) + bf2f(v2.w) + bf2f(v3.w);
    }
    for (; i < cnt; i += 4) {
        ushort4 v = y2b[(size_t)s_lst[sub][i] * 32 + lane];
        ax += bf2f(v.x); ay += bf2f(v.y); az += bf2f(v.z); aw += bf2f(v.w);
    }

    if (grp) { s_red[sub][grp - 1][lane] = make_float4(ax, ay, az, aw); }
    __syncthreads();
    if (grp == 0) {
        float4 r0 = s_red[sub][0][lane];
        float4 r1 = s_red[sub][1][lane];
        float4 r2 = s_red[sub][2][lane];
        float dv = dvih[n];
        float4 bb = ((const float4*)b)[lane];
        float4 o = make_float4((ax + r0.x + r1.x + r2.x) * dv + bb.x,
                               (ay + r0.y + r1.y + r2.y) * dv + bb.y,
                               (az + r0.z + r1.z + r2.z) * dv + bb.z,
                               (aw + r0.w + r1.w + r2.w) * dv + bb.w);
        ((float4*)out)[(size_t)n * 32 + lane] = o;
    }
}

extern "C" void kernel_launch(void* const* d_in, const int* in_sizes, int n_in,
                              void* d_out, int out_size, void* d_ws, size_t ws_size,
                              hipStream_t stream) {
    const float* x = (const float*)d_in[0];   // [16384,128]
    const float* H = (const float*)d_in[1];   // [16384,8192]
    const float* W = (const float*)d_in[2];   // [128,128]
    const float* b = (const float*)d_in[3];   // [128]
    float* out = (float*)d_out;

    char* ws = (char*)d_ws;
    float*   dvih    = (float*)  (ws + 0);
    int*     csr_cnt = (int*)    (ws + 65536);
    int*     edge_cnt= (int*)    (ws + 131072);
    int*     csr_idx = (int*)    (ws + 163840);
    int*     csc_idx = (int*)    (ws + 8552448);
    ushort4* xwb     = (ushort4*)(ws + 14843904);
    ushort4* y2b     = (ushort4*)(ws + 19038208);

    g_gemm<<<NN / 32, 256, 0, stream>>>(x, W, xwb, edge_cnt);
    k1_parse<<<NN, 256, 0, stream>>>(H, dvih, csr_cnt, csr_idx, edge_cnt, csc_idx);
    k2_edge_gather<<<EE / 2, 256, 0, stream>>>(xwb, dvih, edge_cnt, csc_idx, y2b);
    k3_node_gather<<<NN / 2, 256, 0, stream>>>(y2b, dvih, csr_cnt, csr_idx, b, out);
}